// Round 1
// baseline (4418.220 us; speedup 1.0000x reference)
//
#include <hip/hip_runtime.h>

typedef __attribute__((ext_vector_type(8))) short short8;
typedef __attribute__((ext_vector_type(4))) float f32x4;

// ---------- helpers ----------
__device__ __forceinline__ unsigned short f2bu(float x) {
  // round-to-nearest-even f32 -> bf16 (inputs finite)
  unsigned int u = __float_as_uint(x);
  u += 0x7fffu + ((u >> 16) & 1u);
  return (unsigned short)(u >> 16);
}
__device__ __forceinline__ unsigned int pk2(float a, float b) {
  return (unsigned int)f2bu(a) | ((unsigned int)f2bu(b) << 16);
}
__device__ __forceinline__ void gload_lds16(const void* g, void* l) {
  __builtin_amdgcn_global_load_lds((const __attribute__((address_space(1))) unsigned int*)g,
                                   (__attribute__((address_space(3))) unsigned int*)l, 16, 0, 0);
}

// ---------- cast & concat: ins[m][c], c = [M_flow(256) | DT(256) | D(512)] ----------
__global__ void cast_concat_kernel(const float* __restrict__ Mf,
                                   const float* __restrict__ DTf,
                                   const float* __restrict__ Df,
                                   unsigned short* __restrict__ ins) {
  size_t idx = (size_t)blockIdx.x * blockDim.x + threadIdx.x;
  size_t e0 = idx * 8;                 // 8 bf16 per thread, never crosses a region boundary
  size_t m = e0 >> 10;
  int c = (int)(e0 & 1023);
  const float* src;
  if (c < 256)      src = Mf  + m * 256 + c;
  else if (c < 512) src = DTf + m * 256 + (c - 256);
  else              src = Df  + m * 512 + (c - 512);
  float4 f0 = reinterpret_cast<const float4*>(src)[0];
  float4 f1 = reinterpret_cast<const float4*>(src)[1];
  uint4 o;
  o.x = pk2(f0.x, f0.y); o.y = pk2(f0.z, f0.w);
  o.z = pk2(f1.x, f1.y); o.w = pk2(f1.z, f1.w);
  *reinterpret_cast<uint4*>(ins + e0) = o;
}

__global__ void cast_w_kernel(const float* __restrict__ in, unsigned short* __restrict__ out, int n8) {
  int idx = blockIdx.x * blockDim.x + threadIdx.x;
  if (idx >= n8) return;
  const float* src = in + (size_t)idx * 8;
  float4 f0 = reinterpret_cast<const float4*>(src)[0];
  float4 f1 = reinterpret_cast<const float4*>(src)[1];
  uint4 o;
  o.x = pk2(f0.x, f0.y); o.y = pk2(f0.z, f0.w);
  o.z = pk2(f1.x, f1.y); o.w = pk2(f1.z, f1.w);
  *reinterpret_cast<uint4*>(out + (size_t)idx * 8) = o;
}

// ---------- GEMM: C[M][N] = op(A[M][K] * Bt[N][K]^T), bf16 in, f32 acc ----------
// m97 structure: 128x128 tile, BK=32, 4 waves (2x2), global_load_lds width 16.
template <int RELU, typename TOUT>
__global__ __launch_bounds__(256) void gemm_bt_kernel(const unsigned short* __restrict__ A,
                                                      const unsigned short* __restrict__ Bt,
                                                      TOUT* __restrict__ C,
                                                      int M, int N, int K) {
  __shared__ unsigned short As[128 * 32];
  __shared__ unsigned short Bs[128 * 32];
  const int tid = threadIdx.x;
  const int l = tid & 63, w = tid >> 6;
  const int lr = l & 15, lg = l >> 4;
  const int wm = w >> 1, wn = w & 1;
  const int tiles_n = N >> 7;
  const int tm = blockIdx.x / tiles_n, tn = blockIdx.x % tiles_n;
  const int bm0 = tm << 7, bn0 = tn << 7;

  f32x4 acc[4][4] = {};

  for (int kt = 0; kt < K; kt += 32) {
#pragma unroll
    for (int i = 0; i < 2; ++i) {
      int ch = tid + (i << 8);           // chunk 0..511, 16B each
      int row = ch >> 2, cc = ch & 3;
      const unsigned short* ga = A + (size_t)(bm0 + row) * K + kt + cc * 8;
      const unsigned short* gb = Bt + (size_t)(bn0 + row) * K + kt + cc * 8;
      unsigned short* la = As + ((size_t)((i << 8) + (w << 6))) * 8;   // wave-uniform base
      unsigned short* lb = Bs + ((size_t)((i << 8) + (w << 6))) * 8;
      gload_lds16(ga, la);
      gload_lds16(gb, lb);
    }
    __syncthreads();
    short8 af[4], bf[4];
#pragma unroll
    for (int mi = 0; mi < 4; ++mi)
      af[mi] = *reinterpret_cast<const short8*>(As + (wm * 64 + mi * 16 + lr) * 32 + lg * 8);
#pragma unroll
    for (int ni = 0; ni < 4; ++ni)
      bf[ni] = *reinterpret_cast<const short8*>(Bs + (wn * 64 + ni * 16 + lr) * 32 + lg * 8);
#pragma unroll
    for (int mi = 0; mi < 4; ++mi)
#pragma unroll
      for (int ni = 0; ni < 4; ++ni)
        acc[mi][ni] = __builtin_amdgcn_mfma_f32_16x16x32_bf16(af[mi], bf[ni], acc[mi][ni], 0, 0, 0);
    __syncthreads();
  }

#pragma unroll
  for (int mi = 0; mi < 4; ++mi)
#pragma unroll
    for (int ni = 0; ni < 4; ++ni)
#pragma unroll
      for (int r = 0; r < 4; ++r) {
        int row = bm0 + wm * 64 + mi * 16 + lg * 4 + r;
        int col = bn0 + wn * 64 + ni * 16 + lr;
        float v = acc[mi][ni][r];
        if (RELU) v = fmaxf(v, 0.f);
        if constexpr (sizeof(TOUT) == 2) {
          reinterpret_cast<unsigned short*>(C)[(size_t)row * N + col] = f2bu(v);
        } else {
          C[(size_t)row * N + col] = v;
        }
      }
}

// ---------- recurrence: x_t = relu(G[t] + x_{t-1} @ W^T), per-batch-row independent ----------
// 16 blocks x 16 rows; 512 threads = 8 waves, wave w owns 64 output cols.
// x kept in LDS as bf16 [16][512], XOR-swizzled: byte(i,k) = i*1024 + ((2k) ^ ((i&7)<<4)).
__global__ __launch_bounds__(512, 2) void recurrence_kernel(const float* __restrict__ x0,
                                                            const float* __restrict__ G,
                                                            const unsigned short* W,   // no restrict: block licm-hoist of 64 frags
                                                            float* __restrict__ X,
                                                            float* __restrict__ Y) {
  __shared__ char xls[2][16 * 1024];
  const int tid = threadIdx.x;
  const int l = tid & 63, w = tid >> 6;     // w 0..7
  const int lr = l & 15, lg = l >> 4;
  const int r0 = blockIdx.x << 4;           // batch rows r0..r0+15
  const int jb = w << 6;                    // 64 cols per wave

  // init x into buf 0
  {
    int row = tid >> 5;                     // 0..15
    int kc = (tid & 31) << 4;               // 16-elem chunk
    const float* src = x0 + (size_t)(r0 + row) * 512 + kc;
    float4 f0 = reinterpret_cast<const float4*>(src)[0];
    float4 f1 = reinterpret_cast<const float4*>(src)[1];
    float4 f2 = reinterpret_cast<const float4*>(src)[2];
    float4 f3 = reinterpret_cast<const float4*>(src)[3];
    uint4 o0, o1;
    o0.x = pk2(f0.x, f0.y); o0.y = pk2(f0.z, f0.w); o0.z = pk2(f1.x, f1.y); o0.w = pk2(f1.z, f1.w);
    o1.x = pk2(f2.x, f2.y); o1.y = pk2(f2.z, f2.w); o1.z = pk2(f3.x, f3.y); o1.w = pk2(f3.z, f3.w);
    int swz = (row & 7) << 4;
    *reinterpret_cast<uint4*>(xls[0] + row * 1024 + ((kc * 2) ^ swz)) = o0;
    *reinterpret_cast<uint4*>(xls[0] + row * 1024 + ((kc * 2 + 16) ^ swz)) = o1;
  }
  __syncthreads();

  const unsigned short* wb[4];
#pragma unroll
  for (int jt = 0; jt < 4; ++jt)
    wb[jt] = W + (size_t)(jb + jt * 16 + lr) * 512 + lg * 8;

  const int swzA = (lr & 7) << 4;
  int cur = 0;
  for (int t = 0; t < 256; ++t) {
    const float* Gt = G + ((size_t)t * 256 + r0) * 512;
    float* Xt = X + ((size_t)t * 256 + r0) * 512;

    // prefetch G (epilogue operand) early — hides HBM latency under MFMA
    float g[4][4];
#pragma unroll
    for (int jt = 0; jt < 4; ++jt)
#pragma unroll
      for (int r = 0; r < 4; ++r)
        g[jt][r] = Gt[(lg * 4 + r) * 512 + jb + jt * 16 + lr];

    // A fragments: 16 swizzled ds_read_b128 from current x buffer
    short8 a[16];
#pragma unroll
    for (int kk = 0; kk < 16; ++kk) {
      int kb = kk * 64 + lg * 16;
      a[kk] = *reinterpret_cast<const short8*>(xls[cur] + lr * 1024 + (kb ^ swzA));
    }

    f32x4 acc[4] = {};
    short8 b0[16], b1[16];
#pragma unroll
    for (int kk = 0; kk < 16; ++kk)
      b0[kk] = *reinterpret_cast<const short8*>(wb[0] + kk * 32);
#pragma unroll
    for (int jt = 0; jt < 4; ++jt) {
      const short8* bc = (jt & 1) ? b1 : b0;
      short8* bn = (jt & 1) ? b0 : b1;
      if (jt < 3) {
#pragma unroll
        for (int kk = 0; kk < 16; ++kk)
          bn[kk] = *reinterpret_cast<const short8*>(wb[jt + 1] + kk * 32);
      }
#pragma unroll
      for (int kk = 0; kk < 16; ++kk)
        acc[jt] = __builtin_amdgcn_mfma_f32_16x16x32_bf16(a[kk], bc[kk], acc[jt], 0, 0, 0);
    }

    // epilogue: relu(G + acc) -> X global, bf16 -> LDS (next buf), Y for j==511
    char* xw = xls[cur ^ 1];
#pragma unroll
    for (int jt = 0; jt < 4; ++jt)
#pragma unroll
      for (int r = 0; r < 4; ++r) {
        float v = fmaxf(g[jt][r] + acc[jt][r], 0.f);
        int i = lg * 4 + r;
        int j = jb + jt * 16 + lr;
        Xt[(size_t)i * 512 + j] = v;
        *reinterpret_cast<unsigned short*>(xw + i * 1024 + ((j * 2) ^ ((i & 7) << 4))) = f2bu(v);
        if (j == 511) Y[t * 256 + r0 + i] = v;
      }
    __syncthreads();
    cur ^= 1;
  }
}

// ---------- launch ----------
extern "C" void kernel_launch(void* const* d_in, const int* in_sizes, int n_in,
                              void* d_out, int out_size, void* d_ws, size_t ws_size,
                              hipStream_t stream) {
  const float* x0   = (const float*)d_in[0];
  const float* Mf   = (const float*)d_in[1];
  const float* DTf  = (const float*)d_in[2];
  const float* Df   = (const float*)d_in[3];
  const float* Wih0 = (const float*)d_in[4];
  // d_in[5] = W_hh0: unused by the reference
  const float* Wih1 = (const float*)d_in[6];
  const float* Whh1 = (const float*)d_in[7];

  char* ws = (char*)d_ws;
  unsigned short* ins = (unsigned short*)(ws);                 // 134217728 B [65536][1024] bf16
  unsigned short* H   = (unsigned short*)(ws + 134217728ULL);  // 134217728 B [65536][1024] bf16
  unsigned short* w0b = (unsigned short*)(ws + 268435456ULL);  // 2 MB
  unsigned short* w1b = (unsigned short*)(ws + 270532608ULL);  // 1 MB
  unsigned short* whb = (unsigned short*)(ws + 271581184ULL);  // 0.5 MB
  float* G = (float*)(ws);                                     // aliases ins (dead after GEMM1)

  cast_concat_kernel<<<32768, 256, 0, stream>>>(Mf, DTf, Df, ins);
  cast_w_kernel<<<512, 256, 0, stream>>>(Wih0, w0b, 131072);
  cast_w_kernel<<<256, 256, 0, stream>>>(Wih1, w1b, 65536);
  cast_w_kernel<<<128, 256, 0, stream>>>(Whh1, whb, 32768);

  // H = relu(ins @ W_ih0^T): M=65536 N=1024 K=1024
  gemm_bt_kernel<1, unsigned short><<<(65536 / 128) * (1024 / 128), 256, 0, stream>>>(
      ins, w0b, H, 65536, 1024, 1024);
  // G = H @ W_ih1^T: M=65536 N=512 K=1024 (f32 out, no relu)
  gemm_bt_kernel<0, float><<<(65536 / 128) * (512 / 128), 256, 0, stream>>>(
      H, w1b, G, 65536, 512, 1024);

  float* X = (float*)d_out;
  float* Y = X + 33554432;
  recurrence_kernel<<<16, 512, 0, stream>>>(x0, G, whb, X, Y);
}